// Round 5
// baseline (1328.378 us; speedup 1.0000x reference)
//
#include <hip/hip_runtime.h>
#include <hip/hip_cooperative_groups.h>
#include <stdint.h>

// FCOS head, MI355X. Implicit-GEMM conv3x3 via bf16 MFMA (16x16x32), activations
// NHWC bf16, global_load_lds(16B) staging. K-loop: R5 3-buffer LDS ring with RAW
// s_barrier + explicit s_waitcnt vmcnt(N) (measured local optimum, 163 us).
// R1 lesson: 256x128@72KB LDS drops residency, -22%.
// R2/R3 lesson: ANY source change inside conv_mfma (even epilogue-only)
//   perturbs K-loop codegen (VGPR 92->100) and breaks the vmcnt(4) schedule.
//   conv_mfma is frozen (R4-exact, incl. XCD swizzle: FETCH -40%, time neutral).
// R5: gn_stats+gn_apply fused into ONE cooperative kernel per stage
//   (grid-stride stats -> grid.sync -> grid-stride apply with LDS-cached
//   mean/rstd and gamma/beta). Saves 3 dispatches + gaps + apply-side
//   per-element division/rsqrt.

namespace cg = cooperative_groups;

typedef __attribute__((ext_vector_type(8))) short short8;
typedef __attribute__((ext_vector_type(4))) float floatx4;

__device__ __forceinline__ unsigned short f2bf(float f) {
  unsigned u = __float_as_uint(f);
  u = (u + 0x7FFFu + ((u >> 16) & 1u)) >> 16;   // RNE
  return (unsigned short)u;
}
__device__ __forceinline__ unsigned pk2(float a, float b) {
  return (unsigned)f2bf(a) | ((unsigned)f2bf(b) << 16);
}
__device__ __forceinline__ void async16(const void* g, void* l) {
  __builtin_amdgcn_global_load_lds(
      (const __attribute__((address_space(1))) unsigned int*)g,
      (__attribute__((address_space(3))) unsigned int*)l, 16, 0, 0);
}

// s_waitcnt imm16 (gfx9 enc): vmcnt[3:0]|[15:14], expcnt[6:4], lgkmcnt[11:8]
#define WAIT_VM4 0x0F74   // vmcnt(4), exp/lgkm unconstrained
#define WAIT_VM0 0x0F70   // vmcnt(0)

// level geometry (fixed by problem): W = 1<<lw, HW = 1<<(2lw)
__device__ const int d_lw[5]   = {7, 6, 5, 4, 3};
__device__ const int d_off[5]  = {0, 16384, 20480, 21504, 21760};
__device__ const int d_nt[5]   = {128, 32, 8, 2, 1};           // ceil(HW/128)
__device__ const int d_cumT[6] = {0, 1024, 1280, 1344, 1360, 1368}; // 8*nt per level
__device__ const int d_cumO[6] = {0, 512, 640, 672, 680, 684};      // 4*nt per level
__device__ const int d_cumS[6] = {0, 256, 320, 336, 340, 341};      // HW/64 tiles/chunks

// ---------------------------------------------------------------------------
// init: zero page (1536 B, OOB source for global_load_lds) + 3 stage stats
// arrays (3 x 640 floats) -- ws is re-poisoned to 0xAA before every launch.
__global__ void zpk(float* zp, float* stats) {
  for (int i = threadIdx.x; i < 384; i += 256) zp[i] = 0.f;
  for (int i = threadIdx.x; i < 1920; i += 256) stats[i] = 0.f;
}

// ---------------------------------------------------------------------------
// weight transform: fp32 [O][I][3][3] -> bf16 blocked [mt][cc][tap][cs][m][8]
// z: 0..2 cls_w0..2, 3..5 reg_w0..2, 6 cls_out(pad 80->128), 7 reg_out+ctr(pad 5->128)
__global__ __launch_bounds__(256) void wtrans(
    const float* __restrict__ c0, const float* __restrict__ c1, const float* __restrict__ c2,
    const float* __restrict__ r0, const float* __restrict__ r1, const float* __restrict__ r2,
    const float* __restrict__ cw, const float* __restrict__ rw, const float* __restrict__ tw,
    unsigned short* __restrict__ dst) {
  const int z = blockIdx.y;
  const int nel = (z < 6) ? 589824 : 294912;
  const int idx = blockIdx.x * 256 + threadIdx.x;
  if (idx >= nel) return;
  int tmp = idx;
  const int j = tmp & 7;   tmp >>= 3;
  const int m = tmp & 127; tmp >>= 7;
  const int cs = tmp & 3;  tmp >>= 2;
  const int t = tmp % 9;   tmp /= 9;     // tap inner
  const int cc = tmp & 7;  const int mt = tmp >> 3;
  const int o = mt * 128 + m;
  const int i = cc * 32 + cs * 8 + j;
  float v = 0.f;
  const float* srcs[6] = {c0, c1, c2, r0, r1, r2};
  if (z < 6)      v = srcs[z][((size_t)o * 256 + i) * 9 + t];
  else if (z == 6){ if (o < 80) v = cw[((size_t)o * 256 + i) * 9 + t]; }
  else            { if (o < 4)  v = rw[((size_t)o * 256 + i) * 9 + t];
                    else if (o == 4) v = tw[(size_t)i * 9 + t]; }
  const size_t base = (z < 6) ? (size_t)z * 589824
                              : (size_t)6 * 589824 + (size_t)(z - 6) * 294912;
  dst[base + idx] = f2bf(v);
}

// ---------------------------------------------------------------------------
// feature NCHW fp32 -> NHWC bf16 (64x64 LDS tile transpose), all 5 levels in
// one dispatch: blockIdx.x = global position tile (d_cumS), y = ch quarter, z = img.
__global__ __launch_bounds__(256) void feat_nhwc(
    const float* __restrict__ s0, const float* __restrict__ s1,
    const float* __restrict__ s2, const float* __restrict__ s3,
    const float* __restrict__ s4, unsigned short* __restrict__ dst) {
  __shared__ unsigned short tile[64][65];
  int bx = blockIdx.x, lvl = 0;
  while (bx >= d_cumS[lvl + 1]) ++lvl;
  const int HW = 1 << (2 * d_lw[lvl]), off = d_off[lvl];
  const float* srcs[5] = {s0, s1, s2, s3, s4};
  const float* src = srcs[lvl];
  const int img = blockIdx.z, c0 = blockIdx.y * 64, p0 = (bx - d_cumS[lvl]) * 64;
  const float* s = src + ((size_t)img * 256 + c0) * HW + p0;
  const int tid = threadIdx.x;
#pragma unroll
  for (int i = 0; i < 4; i++) {
    const int cl = (tid >> 4) + i * 16, pl = (tid & 15) * 4;
    const float4 v = *(const float4*)(s + (size_t)cl * HW + pl);
    tile[cl][pl]     = f2bf(v.x);
    tile[cl][pl + 1] = f2bf(v.y);
    tile[cl][pl + 2] = f2bf(v.z);
    tile[cl][pl + 3] = f2bf(v.w);
  }
  __syncthreads();
  const int pl = tid >> 2, cseg = (tid & 3) * 16;
  unsigned ro[8];
#pragma unroll
  for (int k = 0; k < 8; k++)
    ro[k] = (unsigned)tile[cseg + 2 * k][pl] | ((unsigned)tile[cseg + 2 * k + 1][pl] << 16);
  unsigned short* dp = dst + ((size_t)img * 21824 + off + p0 + pl) * 256 + c0 + cseg;
  uint4 u0 = {ro[0], ro[1], ro[2], ro[3]};
  uint4 u1 = {ro[4], ro[5], ro[6], ro[7]};
  *(uint4*)dp = u0;
  *(uint4*)(dp + 8) = u1;
}

// ---------------------------------------------------------------------------
// conv3x3 implicit GEMM, 3-buffer LDS ring, raw barrier + fine vmcnt (R5).
// mode 0: tower conv -> y (NHWC bf16, +bias). mode 1: output convs -> d_out.
// FROZEN (R4-exact): body + XCD-chunked bid swizzle.
__global__ __launch_bounds__(256) void conv_mfma(
    const unsigned short* __restrict__ xin0, const unsigned short* __restrict__ xin1,
    const unsigned short* __restrict__ wA, const unsigned short* __restrict__ wB,
    unsigned short* __restrict__ y0, unsigned short* __restrict__ y1,
    const float* __restrict__ cb0, const float* __restrict__ cb1,
    float* __restrict__ out,
    const float* __restrict__ ob_cls, const float* __restrict__ ob_reg, const float* __restrict__ ob_ctr,
    const unsigned short* __restrict__ zp, int mode) {
  __shared__ __align__(16) char smem[49152];   // 3 buffers x (A 8K | B 8K)
  const int tid = threadIdx.x;
  const int* cum = (mode == 0) ? d_cumT : d_cumO;
  // XCD-chunked bijective bid swizzle (T1, m204 variant): consecutive output
  // tiles (same A panel, adjacent B rows) land on one XCD's L2.
  const int nwg = (mode == 0) ? 1368 : 684;
  const int xcd = blockIdx.x & 7, cidx = blockIdx.x >> 3;
  const int qq = nwg >> 3, rr = nwg & 7;
  int bid = (xcd < rr ? xcd * (qq + 1) : rr * (qq + 1) + (xcd - rr) * qq) + cidx;
  int lvl = 0;
  while (bid >= cum[lvl + 1]) ++lvl;
  int r = bid - cum[lvl];
  const int lw = d_lw[lvl], W = 1 << lw, HW = 1 << (2 * lw), poffl = d_off[lvl];
  const int ntc = d_nt[lvl];
  const int nt = r % ntc; r /= ntc;
  int mt = 0;
  if (mode == 0) { mt = r & 1; r >>= 1; }
  const int img = r & 1, tower = r >> 1;

  const unsigned short* xin = (tower ? xin1 : xin0) + (size_t)img * 21824 * 256;
  const unsigned short* wset = tower ? wB : wA;

  // this thread's staged B position (slot n = tid&127, csegs tid>>7 and +2)
  const int n = tid & 127;
  const int p = nt * 128 + n;
  const bool pv = p < HW;
  const int h = p >> lw, w = p & (W - 1);
  const int cs0 = (tid >> 7) * 16;   // byte offset of first cseg

  // per-tap B base pointers (zero page for OOB / padding), statically indexed below
  const char* tb[9];
#pragma unroll
  for (int t = 0; t < 9; t++) {
    const int rr2 = h + t / 3 - 1, cx = w + t % 3 - 1;
    const bool v = pv && rr2 >= 0 && rr2 < W && cx >= 0 && cx < W;
    tb[t] = v ? (const char*)(xin + (size_t)(poffl + rr2 * W + cx) * 256) + cs0
              : (const char*)zp + cs0;
  }

  const char* abase = (const char*)wset + (size_t)mt * 589824;  // bytes per mt panel
  const char* a_tid = abase + (size_t)tid * 16;
  char* l_tid = smem + tid * 16;

  const int lane = tid & 63, q = lane >> 4, lr = lane & 15;
  const int wv = tid >> 6, wm = wv >> 1, wn = wv & 1;
  int aoff[4], boff[4];
#pragma unroll
  for (int i = 0; i < 4; i++) {
    aoff[i] = ((q << 7) + wm * 64 + i * 16 + lr) << 4;
    boff[i] = (((q << 7) + wn * 64 + i * 16 + lr) << 4) + 8192;
  }

  floatx4 acc[4][4];
#pragma unroll
  for (int i = 0; i < 4; i++)
#pragma unroll
    for (int j = 0; j < 4; j++) acc[i][j] = (floatx4){0.f, 0.f, 0.f, 0.f};

  // K order: it = cc*9 + t (cc outer 0..7, tap inner 0..8). Unit it:
  // A (8KB) at a_tid + it*8192; B at tb[it%9] + (it/9)*64. Buffer = it%3.
  // Per unit: waitcnt vmcnt(4) [stage(it) done, stage(it+1) in flight],
  // raw s_barrier, issue stage(it+2), consume buffer it%3.
#define UNIT(CC, U, WIMM)                                                     \
  {                                                                           \
    const int it_ = (CC) * 9 + (U);                                           \
    __builtin_amdgcn_s_waitcnt(WIMM);                                         \
    __builtin_amdgcn_s_barrier();                                             \
    asm volatile("" ::: "memory");                                            \
    if (it_ + 2 < 72) {                                                       \
      const int nu_ = (U) + 2;                                                \
      const int tn_ = nu_ % 9;            /* compile-time */                  \
      const int ccn_ = (CC) + nu_ / 9;                                        \
      char* la_ = l_tid + (nu_ % 3) * 16384;                                  \
      const char* ap_ = a_tid + (size_t)(it_ + 2) * 8192;                     \
      async16(ap_, la_);                                                      \
      async16(ap_ + 4096, la_ + 4096);                                        \
      const char* bp_ = tb[tn_] + ccn_ * 64;                                  \
      async16(bp_, la_ + 8192);                                               \
      async16(bp_ + 32, la_ + 12288);                                         \
    }                                                                         \
    asm volatile("" ::: "memory");                                            \
    const int sb_ = ((U) % 3) * 16384;                                        \
    short8 af[4], bfr[4];                                                     \
    _Pragma("unroll")                                                         \
    for (int i = 0; i < 4; i++) {                                             \
      af[i] = *(const short8*)(smem + sb_ + aoff[i]);                         \
      bfr[i] = *(const short8*)(smem + sb_ + boff[i]);                        \
    }                                                                         \
    _Pragma("unroll")                                                         \
    for (int i = 0; i < 4; i++)                                               \
      _Pragma("unroll")                                                       \
      for (int j = 0; j < 4; j++)                                             \
        acc[i][j] = __builtin_amdgcn_mfma_f32_16x16x32_bf16(af[i], bfr[j],    \
                                                            acc[i][j], 0, 0, 0); \
  }

  // prologue: stage units 0 and 1 into buffers 0 and 1
  async16(a_tid, l_tid);
  async16(a_tid + 4096, l_tid + 4096);
  async16(tb[0], l_tid + 8192);
  async16(tb[0] + 32, l_tid + 12288);
  async16(a_tid + 8192, l_tid + 16384);
  async16(a_tid + 12288, l_tid + 20480);
  async16(tb[1], l_tid + 24576);
  async16(tb[1] + 32, l_tid + 28672);

  for (int cc = 0; cc < 7; ++cc) {
#pragma unroll
    for (int u = 0; u < 9; ++u) UNIT(cc, u, WAIT_VM4)
  }
  // cc = 7 peeled: last 2 units have no younger loads to leave in flight
  UNIT(7, 0, WAIT_VM4) UNIT(7, 1, WAIT_VM4) UNIT(7, 2, WAIT_VM4)
  UNIT(7, 3, WAIT_VM4) UNIT(7, 4, WAIT_VM4) UNIT(7, 5, WAIT_VM4)
  UNIT(7, 6, WAIT_VM4) UNIT(7, 7, WAIT_VM0) UNIT(7, 8, WAIT_VM0)
#undef UNIT

  if (mode == 0) {
    unsigned short* y = (tower ? y1 : y0) + (size_t)img * 21824 * 256;
    const float* cb = tower ? cb1 : cb0;
#pragma unroll
    for (int j = 0; j < 4; j++) {
      const int pp = nt * 128 + wn * 64 + j * 16 + lr;
      if (pp >= HW) continue;
      unsigned short* yr = y + (size_t)(poffl + pp) * 256;
#pragma unroll
      for (int i = 0; i < 4; i++) {
        const int c = mt * 128 + wm * 64 + i * 16 + (q << 2);
        const float4 b4 = *(const float4*)(cb + c);
        floatx4 a = acc[i][j];
        uint2 u;
        u.x = pk2(a.x + b4.x, a.y + b4.y);
        u.y = pk2(a.z + b4.z, a.w + b4.w);
        *(uint2*)(yr + c) = u;
      }
    }
  } else {
#pragma unroll
    for (int j = 0; j < 4; j++) {
      const int pp = nt * 128 + wn * 64 + j * 16 + lr;
      if (pp >= HW) continue;
      const size_t gp = (size_t)poffl + pp;
#pragma unroll
      for (int i = 0; i < 4; i++) {
        const int m0 = wm * 64 + i * 16 + (q << 2);
        floatx4 a = acc[i][j];
#pragma unroll
        for (int k2 = 0; k2 < 4; k2++) {
          const int m = m0 + k2;
          const float v = a[k2];
          if (tower == 0) {
            if (m < 80) out[((size_t)img * 85 + m) * 21824 + gp] = v + ob_cls[m];
          } else {
            if (m < 4)
              out[((size_t)img * 85 + 80 + m) * 21824 + gp] = fmaxf(v + ob_reg[m], 0.f);
            else if (m == 4)
              out[((size_t)img * 85 + 84) * 21824 + gp] = v + ob_ctr[0];
          }
        }
      }
    }
  }
}

// ---------------------------------------------------------------------------
// Fused GN (cooperative, one dispatch per stage):
//   phase 1: grid-stride over 1364 stats tasks (chunk within level x tz);
//            same verified reduction as the old gn_stats.
//   grid.sync()
//   phase 2: grid-stride apply; per-block LDS cache of (mean,rstd) per
//            (tz,lvl,grp) combo + gamma/beta, so the hot loop is
//            load-uint4 / fma / pack / store-uint4 only.
__global__ __launch_bounds__(256) void gn_fused(
    const unsigned short* __restrict__ y0, const unsigned short* __restrict__ y1,
    const unsigned short* __restrict__ ybase, unsigned short* __restrict__ xbase,
    float* __restrict__ stats,
    const float* __restrict__ g0, const float* __restrict__ b0,
    const float* __restrict__ g1, const float* __restrict__ b1) {
  const int tid = threadIdx.x;
  __shared__ float ls[4][32], lq[4][32];

  // ---- phase 1: stats ----
  for (int task = blockIdx.x; task < 1364; task += gridDim.x) {
    const int tz = task / 341;
    const int tower = tz >> 1, img = tz & 1;
    int bx = task % 341, lvl = 0;
    while (bx >= d_cumS[lvl + 1]) ++lvl;
    const int chunk = bx - d_cumS[lvl];
    const int off = d_off[lvl];
    const uint4* y = (const uint4*)((tower ? y1 : y0) + ((size_t)img * 21824 + off) * 256);
    float s = 0.f, s2 = 0.f;
    const int e0 = chunk * 2048 + tid;   // 2048 uint4 per chunk (32 KB)
#pragma unroll
    for (int it = 0; it < 8; ++it) {
      const uint4 d = y[e0 + it * 256];
      unsigned uu[4] = {d.x, d.y, d.z, d.w};
#pragma unroll
      for (int k = 0; k < 4; k++) {
        const float f0 = __uint_as_float(uu[k] << 16);
        const float f1 = __uint_as_float(uu[k] & 0xFFFF0000u);
        s += f0 + f1;
        s2 += f0 * f0 + f1 * f1;
      }
    }
    s += __shfl_down(s, 32);
    s2 += __shfl_down(s2, 32);
    const int lane = tid & 63, wv = tid >> 6;
    if (lane < 32) { ls[wv][lane] = s; lq[wv][lane] = s2; }
    __syncthreads();
    if (tid < 32) {
      const float S = ls[0][tid] + ls[1][tid] + ls[2][tid] + ls[3][tid];
      const float Q = lq[0][tid] + lq[1][tid] + lq[2][tid] + lq[3][tid];
      ls[0][tid] = S; lq[0][tid] = Q;
    }
    __syncthreads();
    if (tid < 16) {
      float* st = stats + (((tz * 5 + lvl) * 16 + tid) << 1);
      atomicAdd(st, ls[0][2 * tid] + ls[0][2 * tid + 1]);
      atomicAdd(st + 1, lq[0][2 * tid] + lq[0][2 * tid + 1]);
    }
    __syncthreads();   // protect ls/lq before next task
  }

  __threadfence();
  cg::this_grid().sync();

  // ---- phase 2: apply ----
  __shared__ float smean[320], srstd[320];
  __shared__ float sgb[2][2][256];   // [tower][gamma/beta][c]
  sgb[0][0][tid] = g0[tid]; sgb[0][1][tid] = b0[tid];
  sgb[1][0][tid] = g1[tid]; sgb[1][1][tid] = b1[tid];
  for (int i = tid; i < 320; i += 256) {
    const int lvl = (i >> 4) % 5;
    const float cnt = (float)(16 << (2 * d_lw[lvl]));
    const float mean = stats[2 * i] / cnt;
    const float var = stats[2 * i + 1] / cnt - mean * mean;
    smean[i] = mean;
    srstd[i] = rsqrtf(var + 1e-5f);
  }
  __syncthreads();

  const size_t nslot = 5586944ull;   // 2 towers x 2 imgs x 21824 pos x 32 uint4
  for (size_t slot = (size_t)blockIdx.x * 256 + tid; slot < nslot;
       slot += (size_t)gridDim.x * 256) {
    const size_t e = slot * 8;
    const int c = (int)(e & 255);
    const size_t pg = e >> 8;
    const int gpos = (int)(pg % 21824);
    const int ti = (int)(pg / 21824);
    const int tower = ti >> 1;
    const int lvl = (gpos >= 16384) + (gpos >= 20480) + (gpos >= 21504) + (gpos >= 21760);
    const int combo = (ti * 5 + lvl) * 16 + (c >> 4);
    const float mean = smean[combo], rstd = srstd[combo];
    uint4 d = *(const uint4*)(ybase + e);
    unsigned uu[4] = {d.x, d.y, d.z, d.w};
    unsigned ro[4];
#pragma unroll
    for (int k = 0; k < 4; k++) {
      const float f0 = __uint_as_float(uu[k] << 16);
      const float f1 = __uint_as_float(uu[k] & 0xFFFF0000u);
      const float o0 = fmaxf((f0 - mean) * rstd * sgb[tower][0][c + 2 * k] + sgb[tower][1][c + 2 * k], 0.f);
      const float o1 = fmaxf((f1 - mean) * rstd * sgb[tower][0][c + 2 * k + 1] + sgb[tower][1][c + 2 * k + 1], 0.f);
      ro[k] = (unsigned)f2bf(o0) | ((unsigned)f2bf(o1) << 16);
    }
    uint4 od = {ro[0], ro[1], ro[2], ro[3]};
    *(uint4*)(xbase + e) = od;
  }
}

// ---------------------------------------------------------------------------
extern "C" void kernel_launch(void* const* d_in, const int* in_sizes, int n_in,
                              void* d_out, int out_size, void* d_ws, size_t ws_size,
                              hipStream_t stream) {
  (void)in_sizes; (void)n_in; (void)out_size; (void)ws_size;
  char* ws = (char*)d_ws;
  unsigned short* zp = (unsigned short*)ws;                 // 1536 B zeros
  unsigned short* wblk = (unsigned short*)(ws + 2048);      // 8,257,536 B
  const size_t WSET_T = 1179648;                            // bytes per tower set
  const size_t WSET_O = 589824;                             // bytes per out set
  char* pXfeat = ws + 2048 + 6 * WSET_T + 2 * WSET_O;
  const size_t XSZ = (size_t)2 * 21824 * 256 * 2;           // 22,347,776 B
  char* pX = pXfeat + XSZ;                                  // 2 towers
  char* pY = pX + 2 * XSZ;                                  // 2 towers
  float* stats = (float*)(pY + 2 * XSZ);                    // 3 stages x 640 floats

  zpk<<<1, 256, 0, stream>>>((float*)zp, stats);
  wtrans<<<dim3(2304, 8), 256, 0, stream>>>(
      (const float*)d_in[5], (const float*)d_in[9], (const float*)d_in[13],
      (const float*)d_in[17], (const float*)d_in[21], (const float*)d_in[25],
      (const float*)d_in[29], (const float*)d_in[31], (const float*)d_in[33], wblk);
  feat_nhwc<<<dim3(341, 4, 2), 256, 0, stream>>>(
      (const float*)d_in[0], (const float*)d_in[1], (const float*)d_in[2],
      (const float*)d_in[3], (const float*)d_in[4], (unsigned short*)pXfeat);

  unsigned short* xc = (unsigned short*)pX;
  unsigned short* xr = (unsigned short*)(pX + XSZ);
  unsigned short* yc = (unsigned short*)pY;
  unsigned short* yr = (unsigned short*)(pY + XSZ);

  for (int s = 0; s < 3; s++) {
    const unsigned short* in0 = s ? xc : (unsigned short*)pXfeat;
    const unsigned short* in1 = s ? xr : (unsigned short*)pXfeat;
    const unsigned short* wc = wblk + (size_t)s * 589824;        // elem stride per set
    const unsigned short* wr = wblk + (size_t)(3 + s) * 589824;
    float* st_s = stats + (size_t)s * 640;
    conv_mfma<<<1368, 256, 0, stream>>>(
        in0, in1, wc, wr, yc, yr,
        (const float*)d_in[6 + 4 * s], (const float*)d_in[18 + 4 * s],
        nullptr, nullptr, nullptr, nullptr, zp, 0);
    // fused GN: stats -> grid.sync -> apply, one cooperative dispatch
    const unsigned short* y0a = yc;
    const unsigned short* y1a = yr;
    const unsigned short* ybase_p = (const unsigned short*)pY;
    unsigned short* xbase_p = (unsigned short*)pX;
    const float* gg0 = (const float*)d_in[7 + 4 * s];
    const float* bb0 = (const float*)d_in[8 + 4 * s];
    const float* gg1 = (const float*)d_in[19 + 4 * s];
    const float* bb1 = (const float*)d_in[20 + 4 * s];
    void* kargs[] = {(void*)&y0a, (void*)&y1a, (void*)&ybase_p, (void*)&xbase_p,
                     (void*)&st_s, (void*)&gg0, (void*)&bb0, (void*)&gg1, (void*)&bb1};
    hipLaunchCooperativeKernel((const void*)gn_fused, dim3(1024), dim3(256),
                               kargs, 0, stream);
  }
  const unsigned short* wo_c = wblk + (size_t)6 * 589824;
  const unsigned short* wo_r = wo_c + 294912;
  conv_mfma<<<684, 256, 0, stream>>>(
      xc, xr, wo_c, wo_r, nullptr, nullptr, nullptr, nullptr,
      (float*)d_out, (const float*)d_in[30], (const float*)d_in[32],
      (const float*)d_in[34], zp, 1);
}

// Round 6
// 637.293 us; speedup vs baseline: 2.0844x; 2.0844x over previous
//
#include <hip/hip_runtime.h>
#include <stdint.h>

// FCOS head, MI355X. Implicit-GEMM conv3x3 via bf16 MFMA (16x16x32).
// K-loop: R5 3-buffer LDS ring, RAW s_barrier + counted vmcnt(4) (frozen
// schedule). XCD-chunked bid swizzle (R4: FETCH -40%, time neutral -> conv is
// VMEM line-REQUEST-throughput-bound, not miss-bound).
// R6: activations stored plane-blocked [cc*4+q][pos][16B] (plane stride XP)
// instead of NHWC -> B staging global_load_lds is fully coalesced (8 lines
// per wave-instr vs 64; per-unit line requests 640->128). LDS image is
// byte-identical, so MFMA/ds_read/schedule untouched. OOB via per-tap stride
// reg (stp=0 -> all invalid lanes read zp+0). Producers (feat_nhwc, gn_apply)
// write the new layout coalesced. Y stays NHWC; gn_stats R0-exact.
// R1: bigger tile kills residency. R2/R3: epilogue atomics serialize block
// retirement (-65%) -- no atomics in conv. R5: cooperative GN fusion -120%.

typedef __attribute__((ext_vector_type(8))) short short8;
typedef __attribute__((ext_vector_type(4))) float floatx4;

#define XP 349184            // plane stride bytes = 21824 * 16
#define TIB (32 * XP)        // per (tower,img) block = 11,173,888 B

__device__ __forceinline__ unsigned short f2bf(float f) {
  unsigned u = __float_as_uint(f);
  u = (u + 0x7FFFu + ((u >> 16) & 1u)) >> 16;   // RNE
  return (unsigned short)u;
}
__device__ __forceinline__ unsigned pk2(float a, float b) {
  return (unsigned)f2bf(a) | ((unsigned)f2bf(b) << 16);
}
__device__ __forceinline__ void async16(const void* g, void* l) {
  __builtin_amdgcn_global_load_lds(
      (const __attribute__((address_space(1))) unsigned int*)g,
      (__attribute__((address_space(3))) unsigned int*)l, 16, 0, 0);
}

// s_waitcnt imm16 (gfx9 enc): vmcnt[3:0]|[15:14], expcnt[6:4], lgkmcnt[11:8]
#define WAIT_VM4 0x0F74   // vmcnt(4), exp/lgkm unconstrained
#define WAIT_VM0 0x0F70   // vmcnt(0)

// level geometry (fixed by problem): W = 1<<lw, HW = 1<<(2lw)
__device__ const int d_lw[5]   = {7, 6, 5, 4, 3};
__device__ const int d_off[5]  = {0, 16384, 20480, 21504, 21760};
__device__ const int d_nt[5]   = {128, 32, 8, 2, 1};           // ceil(HW/128)
__device__ const int d_cumT[6] = {0, 1024, 1280, 1344, 1360, 1368}; // 8*nt per level
__device__ const int d_cumO[6] = {0, 512, 640, 672, 680, 684};      // 4*nt per level
__device__ const int d_cumS[6] = {0, 256, 320, 336, 340, 341};      // HW/64 tiles/chunks

// ---------------------------------------------------------------------------
// init: zero page (1536 B, OOB source for global_load_lds; only zp[0..16) is
// ever read now) + 3 stage stats arrays.
__global__ void zpk(float* zp, float* stats) {
  for (int i = threadIdx.x; i < 384; i += 256) zp[i] = 0.f;
  for (int i = threadIdx.x; i < 1920; i += 256) stats[i] = 0.f;
}

// ---------------------------------------------------------------------------
// weight transform: fp32 [O][I][3][3] -> bf16 blocked [mt][cc][tap][cs][m][8]
// z: 0..2 cls_w0..2, 3..5 reg_w0..2, 6 cls_out(pad 80->128), 7 reg_out+ctr(pad 5->128)
__global__ __launch_bounds__(256) void wtrans(
    const float* __restrict__ c0, const float* __restrict__ c1, const float* __restrict__ c2,
    const float* __restrict__ r0, const float* __restrict__ r1, const float* __restrict__ r2,
    const float* __restrict__ cw, const float* __restrict__ rw, const float* __restrict__ tw,
    unsigned short* __restrict__ dst) {
  const int z = blockIdx.y;
  const int nel = (z < 6) ? 589824 : 294912;
  const int idx = blockIdx.x * 256 + threadIdx.x;
  if (idx >= nel) return;
  int tmp = idx;
  const int j = tmp & 7;   tmp >>= 3;
  const int m = tmp & 127; tmp >>= 7;
  const int cs = tmp & 3;  tmp >>= 2;
  const int t = tmp % 9;   tmp /= 9;     // tap inner
  const int cc = tmp & 7;  const int mt = tmp >> 3;
  const int o = mt * 128 + m;
  const int i = cc * 32 + cs * 8 + j;
  float v = 0.f;
  const float* srcs[6] = {c0, c1, c2, r0, r1, r2};
  if (z < 6)      v = srcs[z][((size_t)o * 256 + i) * 9 + t];
  else if (z == 6){ if (o < 80) v = cw[((size_t)o * 256 + i) * 9 + t]; }
  else            { if (o < 4)  v = rw[((size_t)o * 256 + i) * 9 + t];
                    else if (o == 4) v = tw[(size_t)i * 9 + t]; }
  const size_t base = (z < 6) ? (size_t)z * 589824
                              : (size_t)6 * 589824 + (size_t)(z - 6) * 294912;
  dst[base + idx] = f2bf(v);
}

// ---------------------------------------------------------------------------
// feature NCHW fp32 -> plane-blocked bf16 [img][plane=ch>>3][pos][16B].
// 64x64 LDS tile transpose; blockIdx.x = position tile (d_cumS), y = ch
// quarter, z = img.
__global__ __launch_bounds__(256) void feat_nhwc(
    const float* __restrict__ s0, const float* __restrict__ s1,
    const float* __restrict__ s2, const float* __restrict__ s3,
    const float* __restrict__ s4, unsigned short* __restrict__ dst) {
  __shared__ unsigned short tile[64][65];
  int bx = blockIdx.x, lvl = 0;
  while (bx >= d_cumS[lvl + 1]) ++lvl;
  const int HW = 1 << (2 * d_lw[lvl]), off = d_off[lvl];
  const float* srcs[5] = {s0, s1, s2, s3, s4};
  const float* src = srcs[lvl];
  const int img = blockIdx.z, c0 = blockIdx.y * 64, p0 = (bx - d_cumS[lvl]) * 64;
  const float* s = src + ((size_t)img * 256 + c0) * HW + p0;
  const int tid = threadIdx.x;
#pragma unroll
  for (int i = 0; i < 4; i++) {
    const int cl = (tid >> 4) + i * 16, pl = (tid & 15) * 4;
    const float4 v = *(const float4*)(s + (size_t)cl * HW + pl);
    tile[cl][pl]     = f2bf(v.x);
    tile[cl][pl + 1] = f2bf(v.y);
    tile[cl][pl + 2] = f2bf(v.z);
    tile[cl][pl + 3] = f2bf(v.w);
  }
  __syncthreads();
  const int pl = tid >> 2, cseg = (tid & 3) * 16;
  unsigned ro[8];
#pragma unroll
  for (int k = 0; k < 8; k++)
    ro[k] = (unsigned)tile[cseg + 2 * k][pl] | ((unsigned)tile[cseg + 2 * k + 1][pl] << 16);
  const int ch0 = c0 + cseg;                      // multiple of 16
  char* db = (char*)dst + (size_t)img * TIB + (size_t)(ch0 >> 3) * XP
           + (size_t)(off + p0 + pl) * 16;
  uint4 u0 = {ro[0], ro[1], ro[2], ro[3]};
  uint4 u1 = {ro[4], ro[5], ro[6], ro[7]};
  *(uint4*)db = u0;                               // plane ch0>>3
  *(uint4*)(db + XP) = u1;                        // plane ch0>>3 + 1
}

// ---------------------------------------------------------------------------
// conv3x3 implicit GEMM, 3-buffer LDS ring, raw barrier + fine vmcnt.
// B input layout: plane-blocked [cc*4+q][pos][16B]; staged loads are fully
// coalesced (lane i -> base + i*16). LDS image identical to NHWC version.
// mode 0: tower conv -> y (NHWC bf16, +bias). mode 1: output convs -> d_out.
__global__ __launch_bounds__(256) void conv_mfma(
    const unsigned short* __restrict__ xin0, const unsigned short* __restrict__ xin1,
    const unsigned short* __restrict__ wA, const unsigned short* __restrict__ wB,
    unsigned short* __restrict__ y0, unsigned short* __restrict__ y1,
    const float* __restrict__ cb0, const float* __restrict__ cb1,
    float* __restrict__ out,
    const float* __restrict__ ob_cls, const float* __restrict__ ob_reg, const float* __restrict__ ob_ctr,
    const unsigned short* __restrict__ zp, int mode) {
  __shared__ __align__(16) char smem[49152];   // 3 buffers x (A 8K | B 8K)
  const int tid = threadIdx.x;
  const int* cum = (mode == 0) ? d_cumT : d_cumO;
  // XCD-chunked bijective bid swizzle (T1, m204 variant).
  const int nwg = (mode == 0) ? 1368 : 684;
  const int xcd = blockIdx.x & 7, cidx = blockIdx.x >> 3;
  const int qq = nwg >> 3, rr = nwg & 7;
  int bid = (xcd < rr ? xcd * (qq + 1) : rr * (qq + 1) + (xcd - rr) * qq) + cidx;
  int lvl = 0;
  while (bid >= cum[lvl + 1]) ++lvl;
  int r = bid - cum[lvl];
  const int lw = d_lw[lvl], W = 1 << lw, HW = 1 << (2 * lw), poffl = d_off[lvl];
  const int ntc = d_nt[lvl];
  const int nt = r % ntc; r /= ntc;
  int mt = 0;
  if (mode == 0) { mt = r & 1; r >>= 1; }
  const int img = r & 1, tower = r >> 1;

  const unsigned short* xin = (tower ? xin1 : xin0) + (size_t)img * 21824 * 256;
  const unsigned short* wset = tower ? wB : wA;

  // this thread's staged B slot: pos n = tid&127, k-quad kq = tid>>7 (and kq+2)
  const int n = tid & 127;
  const int p = nt * 128 + n;
  const bool pv = p < HW;
  const int h = p >> lw, w = p & (W - 1);
  const int kq = tid >> 7;

  // per-tap base pointer + stride reg: valid -> plane kq at tap position;
  // invalid -> zp with stride 0 (all derived addrs stay at zp).
  const char* xb = (const char*)xin;
  const char* tb[9];
  int stp[9];
#pragma unroll
  for (int t = 0; t < 9; t++) {
    const int rr2 = h + t / 3 - 1, cx = w + t % 3 - 1;
    const bool v = pv && rr2 >= 0 && rr2 < W && cx >= 0 && cx < W;
    tb[t] = v ? xb + (size_t)kq * XP + (size_t)(poffl + rr2 * W + cx) * 16
              : (const char*)zp;
    stp[t] = v ? 4 * XP : 0;
  }

  const char* abase = (const char*)wset + (size_t)mt * 589824;  // bytes per mt panel
  const char* a_tid = abase + (size_t)tid * 16;
  char* l_tid = smem + tid * 16;

  const int lane = tid & 63, q = lane >> 4, lr = lane & 15;
  const int wv = tid >> 6, wm = wv >> 1, wn = wv & 1;
  int aoff[4], boff[4];
#pragma unroll
  for (int i = 0; i < 4; i++) {
    aoff[i] = ((q << 7) + wm * 64 + i * 16 + lr) << 4;
    boff[i] = (((q << 7) + wn * 64 + i * 16 + lr) << 4) + 8192;
  }

  floatx4 acc[4][4];
#pragma unroll
  for (int i = 0; i < 4; i++)
#pragma unroll
    for (int j = 0; j < 4; j++) acc[i][j] = (floatx4){0.f, 0.f, 0.f, 0.f};

  // K order: it = cc*9 + t (cc outer 0..7, tap inner 0..8). Unit it:
  // A (8KB) at a_tid + it*8192; B planes (cc*4+kq / +2) at tb[it%9].
  // Buffer = it%3. Per unit: vmcnt(4), raw s_barrier, issue stage(it+2),
  // consume buffer it%3.
#define UNIT(CC, U, WIMM)                                                     \
  {                                                                           \
    const int it_ = (CC) * 9 + (U);                                           \
    __builtin_amdgcn_s_waitcnt(WIMM);                                         \
    __builtin_amdgcn_s_barrier();                                             \
    asm volatile("" ::: "memory");                                            \
    if (it_ + 2 < 72) {                                                       \
      const int nu_ = (U) + 2;                                                \
      const int tn_ = nu_ % 9;            /* compile-time */                  \
      const int ccn_ = (CC) + nu_ / 9;                                        \
      char* la_ = l_tid + (nu_ % 3) * 16384;                                  \
      const char* ap_ = a_tid + (size_t)(it_ + 2) * 8192;                     \
      async16(ap_, la_);                                                      \
      async16(ap_ + 4096, la_ + 4096);                                        \
      const int sp_ = stp[tn_];                                               \
      const char* bp_ = tb[tn_] + ccn_ * sp_;                                 \
      async16(bp_, la_ + 8192);                                               \
      async16(bp_ + (sp_ >> 1), la_ + 12288);                                 \
    }                                                                         \
    asm volatile("" ::: "memory");                                            \
    const int sb_ = ((U) % 3) * 16384;                                        \
    short8 af[4], bfr[4];                                                     \
    _Pragma("unroll")                                                         \
    for (int i = 0; i < 4; i++) {                                             \
      af[i] = *(const short8*)(smem + sb_ + aoff[i]);                         \
      bfr[i] = *(const short8*)(smem + sb_ + boff[i]);                        \
    }                                                                         \
    _Pragma("unroll")                                                         \
    for (int i = 0; i < 4; i++)                                               \
      _Pragma("unroll")                                                       \
      for (int j = 0; j < 4; j++)                                             \
        acc[i][j] = __builtin_amdgcn_mfma_f32_16x16x32_bf16(af[i], bfr[j],    \
                                                            acc[i][j], 0, 0, 0); \
  }

  // prologue: stage units 0 and 1 into buffers 0 and 1
  async16(a_tid, l_tid);
  async16(a_tid + 4096, l_tid + 4096);
  async16(tb[0], l_tid + 8192);
  async16(tb[0] + (stp[0] >> 1), l_tid + 12288);
  async16(a_tid + 8192, l_tid + 16384);
  async16(a_tid + 12288, l_tid + 20480);
  async16(tb[1], l_tid + 24576);
  async16(tb[1] + (stp[1] >> 1), l_tid + 28672);

  for (int cc = 0; cc < 7; ++cc) {
#pragma unroll
    for (int u = 0; u < 9; ++u) UNIT(cc, u, WAIT_VM4)
  }
  // cc = 7 peeled: last 2 units have no younger loads to leave in flight
  UNIT(7, 0, WAIT_VM4) UNIT(7, 1, WAIT_VM4) UNIT(7, 2, WAIT_VM4)
  UNIT(7, 3, WAIT_VM4) UNIT(7, 4, WAIT_VM4) UNIT(7, 5, WAIT_VM4)
  UNIT(7, 6, WAIT_VM4) UNIT(7, 7, WAIT_VM0) UNIT(7, 8, WAIT_VM0)
#undef UNIT

  if (mode == 0) {
    unsigned short* y = (tower ? y1 : y0) + (size_t)img * 21824 * 256;
    const float* cb = tower ? cb1 : cb0;
#pragma unroll
    for (int j = 0; j < 4; j++) {
      const int pp = nt * 128 + wn * 64 + j * 16 + lr;
      if (pp >= HW) continue;
      unsigned short* yr = y + (size_t)(poffl + pp) * 256;
#pragma unroll
      for (int i = 0; i < 4; i++) {
        const int c = mt * 128 + wm * 64 + i * 16 + (q << 2);
        const float4 b4 = *(const float4*)(cb + c);
        floatx4 a = acc[i][j];
        uint2 u;
        u.x = pk2(a.x + b4.x, a.y + b4.y);
        u.y = pk2(a.z + b4.z, a.w + b4.w);
        *(uint2*)(yr + c) = u;
      }
    }
  } else {
#pragma unroll
    for (int j = 0; j < 4; j++) {
      const int pp = nt * 128 + wn * 64 + j * 16 + lr;
      if (pp >= HW) continue;
      const size_t gp = (size_t)poffl + pp;
#pragma unroll
      for (int i = 0; i < 4; i++) {
        const int m0 = wm * 64 + i * 16 + (q << 2);
        floatx4 a = acc[i][j];
#pragma unroll
        for (int k2 = 0; k2 < 4; k2++) {
          const int m = m0 + k2;
          const float v = a[k2];
          if (tower == 0) {
            if (m < 80) out[((size_t)img * 85 + m) * 21824 + gp] = v + ob_cls[m];
          } else {
            if (m < 4)
              out[((size_t)img * 85 + 80 + m) * 21824 + gp] = fmaxf(v + ob_reg[m], 0.f);
            else if (m == 4)
              out[((size_t)img * 85 + 84) * 21824 + gp] = v + ob_ctr[0];
          }
        }
      }
    }
  }
}

// ---------------------------------------------------------------------------
// GN stats (R0-exact), coalesced streaming over NHWC Y.
__global__ __launch_bounds__(256) void gn_stats(
    const unsigned short* __restrict__ y0, const unsigned short* __restrict__ y1,
    float* __restrict__ stats) {
  const int tz = blockIdx.z;
  const int tower = tz >> 1, img = tz & 1;
  int bx = blockIdx.x, lvl = 0;
  while (bx >= d_cumS[lvl + 1]) ++lvl;
  const int chunk = bx - d_cumS[lvl];
  const int off = d_off[lvl];
  const uint4* y = (const uint4*)((tower ? y1 : y0) + ((size_t)img * 21824 + off) * 256);
  const int tid = threadIdx.x;
  float s = 0.f, s2 = 0.f;
  const int e0 = chunk * 2048 + tid;   // 2048 uint4 per chunk (32 KB)
#pragma unroll
  for (int it = 0; it < 8; ++it) {
    const uint4 d = y[e0 + it * 256];
    unsigned uu[4] = {d.x, d.y, d.z, d.w};
#pragma unroll
    for (int k = 0; k < 4; k++) {
      const float f0 = __uint_as_float(uu[k] << 16);
      const float f1 = __uint_as_float(uu[k] & 0xFFFF0000u);
      s += f0 + f1;
      s2 += f0 * f0 + f1 * f1;
    }
  }
  s += __shfl_down(s, 32);
  s2 += __shfl_down(s2, 32);
  __shared__ float ls[4][32], lq[4][32];
  const int lane = tid & 63, wv = tid >> 6;
  if (lane < 32) { ls[wv][lane] = s; lq[wv][lane] = s2; }
  __syncthreads();
  if (tid < 32) {
    const float S = ls[0][tid] + ls[1][tid] + ls[2][tid] + ls[3][tid];
    const float Q = lq[0][tid] + lq[1][tid] + lq[2][tid] + lq[3][tid];
    ls[0][tid] = S; lq[0][tid] = Q;
  }
  __syncthreads();
  if (tid < 16) {
    float* st = stats + (((tz * 5 + lvl) * 16 + tid) << 1);
    atomicAdd(st, ls[0][2 * tid] + ls[0][2 * tid + 1]);
    atomicAdd(st + 1, lq[0][2 * tid] + lq[0][2 * tid + 1]);
  }
}

// ---------------------------------------------------------------------------
// GN apply + affine + ReLU + bf16 cast: Y (NHWC) -> X (plane-blocked).
// Thread = one (ti, pos, cc): reads 64B contiguous Y (lane pairs share a full
// 128B line), writes 4 x 16B plane slots (each store instr = 8 full lines).
// grid 2728 x 256 = 4 ti x 21824 pos x 8 cc exactly.
__global__ __launch_bounds__(256) void gn_apply(
    const unsigned short* __restrict__ ybase, unsigned short* __restrict__ xbase,
    const float* __restrict__ stats,
    const float* __restrict__ g0, const float* __restrict__ b0,
    const float* __restrict__ g1, const float* __restrict__ b1) {
  const int g = blockIdx.x * 256 + threadIdx.x;
  const int cc = ((g >> 1) & 3) * 2 + (g & 1);     // 0..7
  const int gg = g >> 3;                           // 0..87295
  const int pos = gg % 21824;
  const int ti = gg / 21824;                       // tower*2+img
  const int tower = ti >> 1;
  const int lvl = (pos >= 16384) + (pos >= 20480) + (pos >= 21504) + (pos >= 21760);
  const float cnt = (float)(16 << (2 * d_lw[lvl]));
  const int cb = (ti * 5 + lvl) * 16 + cc * 2;     // group combo base
  float mean[2], rstd[2];
#pragma unroll
  for (int h2 = 0; h2 < 2; h2++) {
    const float m = stats[2 * (cb + h2)] / cnt;
    const float v = stats[2 * (cb + h2) + 1] / cnt - m * m;
    mean[h2] = m;
    rstd[h2] = rsqrtf(v + 1e-5f);
  }
  const float* gam = (tower ? g1 : g0) + cc * 32;
  const float* bet = (tower ? b1 : b0) + cc * 32;
  const uint4* yp = (const uint4*)(ybase + ((size_t)ti * 21824 + pos) * 256 + cc * 32);
  char* xb = (char*)xbase + (size_t)ti * TIB + (size_t)(cc * 4) * XP + (size_t)pos * 16;
#pragma unroll
  for (int q2 = 0; q2 < 4; q2++) {
    const uint4 d = yp[q2];
    const float m = mean[q2 >> 1], rs = rstd[q2 >> 1];
    unsigned uu[4] = {d.x, d.y, d.z, d.w};
    unsigned ro[4];
#pragma unroll
    for (int k = 0; k < 4; k++) {
      const float f0 = __uint_as_float(uu[k] << 16);
      const float f1 = __uint_as_float(uu[k] & 0xFFFF0000u);
      const float o0 = fmaxf((f0 - m) * rs * gam[q2 * 8 + 2 * k] + bet[q2 * 8 + 2 * k], 0.f);
      const float o1 = fmaxf((f1 - m) * rs * gam[q2 * 8 + 2 * k + 1] + bet[q2 * 8 + 2 * k + 1], 0.f);
      ro[k] = (unsigned)f2bf(o0) | ((unsigned)f2bf(o1) << 16);
    }
    uint4 od = {ro[0], ro[1], ro[2], ro[3]};
    *(uint4*)(xb + (size_t)q2 * XP) = od;
  }
}

// ---------------------------------------------------------------------------
extern "C" void kernel_launch(void* const* d_in, const int* in_sizes, int n_in,
                              void* d_out, int out_size, void* d_ws, size_t ws_size,
                              hipStream_t stream) {
  (void)in_sizes; (void)n_in; (void)out_size; (void)ws_size;
  char* ws = (char*)d_ws;
  unsigned short* zp = (unsigned short*)ws;                 // 1536 B zeros
  unsigned short* wblk = (unsigned short*)(ws + 2048);      // 8,257,536 B
  const size_t WSET_T = 1179648;                            // bytes per tower set
  const size_t WSET_O = 589824;                             // bytes per out set
  char* pXfeat = ws + 2048 + 6 * WSET_T + 2 * WSET_O;
  const size_t XSZ = (size_t)2 * 21824 * 256 * 2;           // 22,347,776 B
  char* pX = pXfeat + XSZ;                                  // 2 towers
  char* pY = pX + 2 * XSZ;                                  // 2 towers
  float* stats = (float*)(pY + 2 * XSZ);                    // 3 stages x 640 floats

  zpk<<<1, 256, 0, stream>>>((float*)zp, stats);
  wtrans<<<dim3(2304, 8), 256, 0, stream>>>(
      (const float*)d_in[5], (const float*)d_in[9], (const float*)d_in[13],
      (const float*)d_in[17], (const float*)d_in[21], (const float*)d_in[25],
      (const float*)d_in[29], (const float*)d_in[31], (const float*)d_in[33], wblk);
  feat_nhwc<<<dim3(341, 4, 2), 256, 0, stream>>>(
      (const float*)d_in[0], (const float*)d_in[1], (const float*)d_in[2],
      (const float*)d_in[3], (const float*)d_in[4], (unsigned short*)pXfeat);

  unsigned short* xc = (unsigned short*)pX;
  unsigned short* xr = (unsigned short*)(pX + XSZ);
  unsigned short* yc = (unsigned short*)pY;
  unsigned short* yr = (unsigned short*)(pY + XSZ);

  for (int s = 0; s < 3; s++) {
    const unsigned short* in0 = s ? xc : (unsigned short*)pXfeat;
    const unsigned short* in1 = s ? xr : (unsigned short*)pXfeat;
    const unsigned short* wc = wblk + (size_t)s * 589824;        // elem stride per set
    const unsigned short* wr = wblk + (size_t)(3 + s) * 589824;
    float* st_s = stats + (size_t)s * 640;
    conv_mfma<<<1368, 256, 0, stream>>>(
        in0, in1, wc, wr, yc, yr,
        (const float*)d_in[6 + 4 * s], (const float*)d_in[18 + 4 * s],
        nullptr, nullptr, nullptr, nullptr, zp, 0);
    gn_stats<<<dim3(341, 1, 4), 256, 0, stream>>>(yc, yr, st_s);
    gn_apply<<<2728, 256, 0, stream>>>(
        (const unsigned short*)pY, (unsigned short*)pX, st_s,
        (const float*)d_in[7 + 4 * s], (const float*)d_in[8 + 4 * s],
        (const float*)d_in[19 + 4 * s], (const float*)d_in[20 + 4 * s]);
  }
  const unsigned short* wo_c = wblk + (size_t)6 * 589824;
  const unsigned short* wo_r = wo_c + 294912;
  conv_mfma<<<684, 256, 0, stream>>>(
      xc, xr, wo_c, wo_r, nullptr, nullptr, nullptr, nullptr,
      (float*)d_out, (const float*)d_in[30], (const float*)d_in[32],
      (const float*)d_in[34], zp, 1);
}

// Round 9
// 600.623 us; speedup vs baseline: 2.2117x; 1.0611x over previous
//
#include <hip/hip_runtime.h>
#include <stdint.h>

// FCOS head, MI355X. Implicit-GEMM conv3x3 via bf16 MFMA (16x16x32).
// Activations plane-blocked [plane=ch>>3][pos][16B] (XP stride) for X (R6)
// and Y (R8) -> staging, epilogue, and GN traffic all coalesced.
// R6: coalesced B staging, 163->107 us (conv was VMEM line-request-bound).
// R7/R8 lesson: identical absmax across two different conv kernels exposed
//   the real bug -- gn_apply grid was 10907 blocks, needs 10912
//   (4 ti x 32 planes x 21824 pos / 256). Last 1280 slots (reg tower img1,
//   plane 31, pos>=20544) stayed poisoned -> moderate deterministic error.
//   R7's "VGPR spill breaks vmcnt" theory is UNPROVEN; conv_t256 may be OK.
// R9: R8 with the gn_apply grid fixed (10912). No other changes.
// R2/R3: no atomics in conv epilogues. R5: no cooperative GN.

typedef __attribute__((ext_vector_type(8))) short short8;
typedef __attribute__((ext_vector_type(4))) float floatx4;

#define XP 349184            // plane stride bytes = 21824 * 16
#define TIB (32 * XP)        // per (tower,img) block = 11,173,888 B

__device__ __forceinline__ unsigned short f2bf(float f) {
  unsigned u = __float_as_uint(f);
  u = (u + 0x7FFFu + ((u >> 16) & 1u)) >> 16;   // RNE
  return (unsigned short)u;
}
__device__ __forceinline__ unsigned pk2(float a, float b) {
  return (unsigned)f2bf(a) | ((unsigned)f2bf(b) << 16);
}
__device__ __forceinline__ void async16(const void* g, void* l) {
  __builtin_amdgcn_global_load_lds(
      (const __attribute__((address_space(1))) unsigned int*)g,
      (__attribute__((address_space(3))) unsigned int*)l, 16, 0, 0);
}

// s_waitcnt imm16 (gfx9 enc): vmcnt[3:0]|[15:14], expcnt[6:4], lgkmcnt[11:8]
#define WAIT_VM4 0x0F74   // vmcnt(4)
#define WAIT_VM0 0x0F70   // vmcnt(0)

// level geometry (fixed by problem): W = 1<<lw, HW = 1<<(2lw)
__device__ const int d_lw[5]   = {7, 6, 5, 4, 3};
__device__ const int d_off[5]  = {0, 16384, 20480, 21504, 21760};
__device__ const int d_nt[5]   = {128, 32, 8, 2, 1};           // ceil(HW/128)
__device__ const int d_cumT[6] = {0, 1024, 1280, 1344, 1360, 1368}; // 8*nt per level
__device__ const int d_cumO[6] = {0, 512, 640, 672, 680, 684};      // 4*nt per level
__device__ const int d_cumS[6] = {0, 256, 320, 336, 340, 341};      // HW/64 tiles
// gn_stats chunk table: 13 chunks x (lvl, pos0, len)
__device__ const int ck_lvl[13] = {0,0,0,0,0,0,0,0,1,1,2,3,4};
__device__ const int ck_c0[13]  = {0,2048,4096,6144,8192,10240,12288,14336,0,2048,0,0,0};
__device__ const int ck_len[13] = {2048,2048,2048,2048,2048,2048,2048,2048,2048,2048,1024,256,64};

// ---------------------------------------------------------------------------
// init: zero page (OOB source for global_load_lds) + 3 stage stats arrays.
__global__ void zpk(float* zp, float* stats) {
  for (int i = threadIdx.x; i < 384; i += 256) zp[i] = 0.f;
  for (int i = threadIdx.x; i < 1920; i += 256) stats[i] = 0.f;
}

// ---------------------------------------------------------------------------
// weight transform: fp32 [O][I][3][3] -> bf16 blocked [mt][cc][tap][cs][m][8]
__global__ __launch_bounds__(256) void wtrans(
    const float* __restrict__ c0, const float* __restrict__ c1, const float* __restrict__ c2,
    const float* __restrict__ r0, const float* __restrict__ r1, const float* __restrict__ r2,
    const float* __restrict__ cw, const float* __restrict__ rw, const float* __restrict__ tw,
    unsigned short* __restrict__ dst) {
  const int z = blockIdx.y;
  const int nel = (z < 6) ? 589824 : 294912;
  const int idx = blockIdx.x * 256 + threadIdx.x;
  if (idx >= nel) return;
  int tmp = idx;
  const int j = tmp & 7;   tmp >>= 3;
  const int m = tmp & 127; tmp >>= 7;
  const int cs = tmp & 3;  tmp >>= 2;
  const int t = tmp % 9;   tmp /= 9;     // tap inner
  const int cc = tmp & 7;  const int mt = tmp >> 3;
  const int o = mt * 128 + m;
  const int i = cc * 32 + cs * 8 + j;
  float v = 0.f;
  const float* srcs[6] = {c0, c1, c2, r0, r1, r2};
  if (z < 6)      v = srcs[z][((size_t)o * 256 + i) * 9 + t];
  else if (z == 6){ if (o < 80) v = cw[((size_t)o * 256 + i) * 9 + t]; }
  else            { if (o < 4)  v = rw[((size_t)o * 256 + i) * 9 + t];
                    else if (o == 4) v = tw[(size_t)i * 9 + t]; }
  const size_t base = (z < 6) ? (size_t)z * 589824
                              : (size_t)6 * 589824 + (size_t)(z - 6) * 294912;
  dst[base + idx] = f2bf(v);
}

// ---------------------------------------------------------------------------
// feature NCHW fp32 -> plane-blocked bf16 (R6-exact).
__global__ __launch_bounds__(256) void feat_nhwc(
    const float* __restrict__ s0, const float* __restrict__ s1,
    const float* __restrict__ s2, const float* __restrict__ s3,
    const float* __restrict__ s4, unsigned short* __restrict__ dst) {
  __shared__ unsigned short tile[64][65];
  int bx = blockIdx.x, lvl = 0;
  while (bx >= d_cumS[lvl + 1]) ++lvl;
  const int HW = 1 << (2 * d_lw[lvl]), off = d_off[lvl];
  const float* srcs[5] = {s0, s1, s2, s3, s4};
  const float* src = srcs[lvl];
  const int img = blockIdx.z, c0 = blockIdx.y * 64, p0 = (bx - d_cumS[lvl]) * 64;
  const float* s = src + ((size_t)img * 256 + c0) * HW + p0;
  const int tid = threadIdx.x;
#pragma unroll
  for (int i = 0; i < 4; i++) {
    const int cl = (tid >> 4) + i * 16, pl = (tid & 15) * 4;
    const float4 v = *(const float4*)(s + (size_t)cl * HW + pl);
    tile[cl][pl]     = f2bf(v.x);
    tile[cl][pl + 1] = f2bf(v.y);
    tile[cl][pl + 2] = f2bf(v.z);
    tile[cl][pl + 3] = f2bf(v.w);
  }
  __syncthreads();
  const int pl = tid >> 2, cseg = (tid & 3) * 16;
  unsigned ro[8];
#pragma unroll
  for (int k = 0; k < 8; k++)
    ro[k] = (unsigned)tile[cseg + 2 * k][pl] | ((unsigned)tile[cseg + 2 * k + 1][pl] << 16);
  const int ch0 = c0 + cseg;                      // multiple of 16
  char* db = (char*)dst + (size_t)img * TIB + (size_t)(ch0 >> 3) * XP
           + (size_t)(off + p0 + pl) * 16;
  uint4 u0 = {ro[0], ro[1], ro[2], ro[3]};
  uint4 u1 = {ro[4], ro[5], ro[6], ro[7]};
  *(uint4*)db = u0;
  *(uint4*)(db + XP) = u1;
}

// ---------------------------------------------------------------------------
// conv3x3 implicit GEMM, 3-buffer LDS ring, raw barrier + counted vmcnt.
// K-loop/staging R6-byte-exact. mode 0: tower conv -> plane-blocked Y (+bias).
// mode 1: output convs -> d_out (R6-exact path).
__global__ __launch_bounds__(256) void conv_mfma(
    const unsigned short* __restrict__ xin0, const unsigned short* __restrict__ xin1,
    const unsigned short* __restrict__ wA, const unsigned short* __restrict__ wB,
    unsigned short* __restrict__ y0, unsigned short* __restrict__ y1,
    const float* __restrict__ cb0, const float* __restrict__ cb1,
    float* __restrict__ out,
    const float* __restrict__ ob_cls, const float* __restrict__ ob_reg, const float* __restrict__ ob_ctr,
    const unsigned short* __restrict__ zp, int mode) {
  __shared__ __align__(16) char smem[49152];   // 3 buffers x (A 8K | B 8K)
  const int tid = threadIdx.x;
  const int* cum = (mode == 0) ? d_cumT : d_cumO;
  const int nwg = (mode == 0) ? 1368 : 684;
  const int xcd = blockIdx.x & 7, cidx = blockIdx.x >> 3;
  const int qq = nwg >> 3, rr = nwg & 7;
  int bid = (xcd < rr ? xcd * (qq + 1) : rr * (qq + 1) + (xcd - rr) * qq) + cidx;
  int lvl = 0;
  while (bid >= cum[lvl + 1]) ++lvl;
  int r = bid - cum[lvl];
  const int lw = d_lw[lvl], W = 1 << lw, HW = 1 << (2 * lw), poffl = d_off[lvl];
  const int ntc = d_nt[lvl];
  const int nt = r % ntc; r /= ntc;
  int mt = 0;
  if (mode == 0) { mt = r & 1; r >>= 1; }
  const int img = r & 1, tower = r >> 1;

  const unsigned short* xin = (tower ? xin1 : xin0) + (size_t)img * 21824 * 256;
  const unsigned short* wset = tower ? wB : wA;

  const int n = tid & 127;
  const int p = nt * 128 + n;
  const bool pv = p < HW;
  const int h = p >> lw, w = p & (W - 1);
  const int kq = tid >> 7;

  const char* xb = (const char*)xin;
  const char* tb[9];
  int stp[9];
#pragma unroll
  for (int t = 0; t < 9; t++) {
    const int rr2 = h + t / 3 - 1, cx = w + t % 3 - 1;
    const bool v = pv && rr2 >= 0 && rr2 < W && cx >= 0 && cx < W;
    tb[t] = v ? xb + (size_t)kq * XP + (size_t)(poffl + rr2 * W + cx) * 16
              : (const char*)zp;
    stp[t] = v ? 4 * XP : 0;
  }

  const char* abase = (const char*)wset + (size_t)mt * 589824;
  const char* a_tid = abase + (size_t)tid * 16;
  char* l_tid = smem + tid * 16;

  const int lane = tid & 63, q = lane >> 4, lr = lane & 15;
  const int wv = tid >> 6, wm = wv >> 1, wn = wv & 1;
  int aoff[4], boff[4];
#pragma unroll
  for (int i = 0; i < 4; i++) {
    aoff[i] = ((q << 7) + wm * 64 + i * 16 + lr) << 4;
    boff[i] = (((q << 7) + wn * 64 + i * 16 + lr) << 4) + 8192;
  }

  floatx4 acc[4][4];
#pragma unroll
  for (int i = 0; i < 4; i++)
#pragma unroll
    for (int j = 0; j < 4; j++) acc[i][j] = (floatx4){0.f, 0.f, 0.f, 0.f};

#define UNIT(CC, U, WIMM)                                                     \
  {                                                                           \
    const int it_ = (CC) * 9 + (U);                                           \
    __builtin_amdgcn_s_waitcnt(WIMM);                                         \
    __builtin_amdgcn_s_barrier();                                             \
    asm volatile("" ::: "memory");                                            \
    if (it_ + 2 < 72) {                                                       \
      const int nu_ = (U) + 2;                                                \
      const int tn_ = nu_ % 9;            /* compile-time */                  \
      const int ccn_ = (CC) + nu_ / 9;                                        \
      char* la_ = l_tid + (nu_ % 3) * 16384;                                  \
      const char* ap_ = a_tid + (size_t)(it_ + 2) * 8192;                     \
      async16(ap_, la_);                                                      \
      async16(ap_ + 4096, la_ + 4096);                                        \
      const int sp_ = stp[tn_];                                               \
      const char* bp_ = tb[tn_] + ccn_ * sp_;                                 \
      async16(bp_, la_ + 8192);                                               \
      async16(bp_ + (sp_ >> 1), la_ + 12288);                                 \
    }                                                                         \
    asm volatile("" ::: "memory");                                            \
    const int sb_ = ((U) % 3) * 16384;                                        \
    short8 af[4], bfr[4];                                                     \
    _Pragma("unroll")                                                         \
    for (int i = 0; i < 4; i++) {                                             \
      af[i] = *(const short8*)(smem + sb_ + aoff[i]);                         \
      bfr[i] = *(const short8*)(smem + sb_ + boff[i]);                        \
    }                                                                         \
    _Pragma("unroll")                                                         \
    for (int i = 0; i < 4; i++)                                               \
      _Pragma("unroll")                                                       \
      for (int j = 0; j < 4; j++)                                             \
        acc[i][j] = __builtin_amdgcn_mfma_f32_16x16x32_bf16(af[i], bfr[j],    \
                                                            acc[i][j], 0, 0, 0); \
  }

  async16(a_tid, l_tid);
  async16(a_tid + 4096, l_tid + 4096);
  async16(tb[0], l_tid + 8192);
  async16(tb[0] + (stp[0] >> 1), l_tid + 12288);
  async16(a_tid + 8192, l_tid + 16384);
  async16(a_tid + 12288, l_tid + 20480);
  async16(tb[1], l_tid + 24576);
  async16(tb[1] + (stp[1] >> 1), l_tid + 28672);

  for (int cc = 0; cc < 7; ++cc) {
#pragma unroll
    for (int u = 0; u < 9; ++u) UNIT(cc, u, WAIT_VM4)
  }
  UNIT(7, 0, WAIT_VM4) UNIT(7, 1, WAIT_VM4) UNIT(7, 2, WAIT_VM4)
  UNIT(7, 3, WAIT_VM4) UNIT(7, 4, WAIT_VM4) UNIT(7, 5, WAIT_VM4)
  UNIT(7, 6, WAIT_VM4) UNIT(7, 7, WAIT_VM0) UNIT(7, 8, WAIT_VM0)
#undef UNIT

  if (mode == 0) {
    // plane-blocked Y write: uint2 at 16B stride; per wave-store, lanes cover
    // 2 planes x 16 consecutive slots = 4 cache lines (vs 64 for NHWC).
    char* yb = (char*)(tower ? y1 : y0) + (size_t)img * TIB;
    const float* cb = tower ? cb1 : cb0;
#pragma unroll
    for (int i = 0; i < 4; i++) {
      const int c = mt * 128 + wm * 64 + i * 16 + (q << 2);
      const float4 b4 = *(const float4*)(cb + c);
      char* yp = yb + (size_t)(c >> 3) * XP + (size_t)poffl * 16 + ((c & 7) << 1);
#pragma unroll
      for (int j = 0; j < 4; j++) {
        const int pp = nt * 128 + wn * 64 + j * 16 + lr;
        if (pp >= HW) continue;
        floatx4 a = acc[i][j];
        uint2 u;
        u.x = pk2(a.x + b4.x, a.y + b4.y);
        u.y = pk2(a.z + b4.z, a.w + b4.w);
        *(uint2*)(yp + (size_t)pp * 16) = u;
      }
    }
  } else {
#pragma unroll
    for (int j = 0; j < 4; j++) {
      const int pp = nt * 128 + wn * 64 + j * 16 + lr;
      if (pp >= HW) continue;
      const size_t gp = (size_t)poffl + pp;
#pragma unroll
      for (int i = 0; i < 4; i++) {
        const int m0 = wm * 64 + i * 16 + (q << 2);
        floatx4 a = acc[i][j];
#pragma unroll
        for (int k2 = 0; k2 < 4; k2++) {
          const int m = m0 + k2;
          const float v = a[k2];
          if (tower == 0) {
            if (m < 80) out[((size_t)img * 85 + m) * 21824 + gp] = v + ob_cls[m];
          } else {
            if (m < 4)
              out[((size_t)img * 85 + 80 + m) * 21824 + gp] = fmaxf(v + ob_reg[m], 0.f);
            else if (m == 4)
              out[((size_t)img * 85 + 84) * 21824 + gp] = v + ob_ctr[0];
          }
        }
      }
    }
  }
}

// ---------------------------------------------------------------------------
// GN stats over plane-blocked Y. Block = (chunk 0..12, group 0..15, tz 0..3).
// All threads reduce ONE group -> single atomicAdd pair per block.
__global__ __launch_bounds__(256) void gn_stats(
    const unsigned short* __restrict__ y0, const unsigned short* __restrict__ y1,
    float* __restrict__ stats) {
  const int ck = blockIdx.x, g = blockIdx.y, tz = blockIdx.z;
  const int tower = tz >> 1, img = tz & 1;
  const int lvl = ck_lvl[ck], c0 = ck_c0[ck], len = ck_len[ck];
  const char* base = (const char*)(tower ? y1 : y0) + (size_t)img * TIB
                   + (size_t)(2 * g) * XP + (size_t)(d_off[lvl] + c0) * 16;
  const int tid = threadIdx.x;
  float s = 0.f, s2 = 0.f;
  const int n2 = 2 * len;
  for (int i = tid; i < n2; i += 256) {
    const int pl = (i >= len);
    const int pos = i - pl * len;
    const uint4 d = *(const uint4*)(base + (size_t)pl * XP + (size_t)pos * 16);
    unsigned uu[4] = {d.x, d.y, d.z, d.w};
#pragma unroll
    for (int k = 0; k < 4; k++) {
      const float f0 = __uint_as_float(uu[k] << 16);
      const float f1 = __uint_as_float(uu[k] & 0xFFFF0000u);
      s += f0 + f1;
      s2 += f0 * f0 + f1 * f1;
    }
  }
#pragma unroll
  for (int m = 1; m < 64; m <<= 1) {
    s += __shfl_xor(s, m);
    s2 += __shfl_xor(s2, m);
  }
  __shared__ float rs[4], rq[4];
  const int lane = tid & 63, wvv = tid >> 6;
  if (lane == 0) { rs[wvv] = s; rq[wvv] = s2; }
  __syncthreads();
  if (tid == 0) {
    float* st = stats + (((tz * 5 + lvl) * 16 + g) << 1);
    atomicAdd(st, rs[0] + rs[1] + rs[2] + rs[3]);
    atomicAdd(st + 1, rq[0] + rq[1] + rq[2] + rq[3]);
  }
}

// ---------------------------------------------------------------------------
// GN apply + affine + ReLU + bf16: Y (plane) -> X (plane). Thread = one 16B
// slot (ti, plane, pos); both sides fully coalesced.
// grid MUST be 10912 = 4 ti x 32 planes x 21824 pos / 256 (R7/R8 bug: 10907).
__global__ __launch_bounds__(256) void gn_apply(
    const unsigned short* __restrict__ ybase, unsigned short* __restrict__ xbase,
    const float* __restrict__ stats,
    const float* __restrict__ g0, const float* __restrict__ b0,
    const float* __restrict__ g1, const float* __restrict__ b1) {
  const int g = blockIdx.x * 256 + threadIdx.x;   // 0..2,793,471 exact
  const int pos = g % 21824;
  const int rest = g / 21824;                     // 0..127
  const int plane = rest & 31;
  const int ti = rest >> 5;                       // tower*2+img
  const int tower = ti >> 1;
  const int lvl = (pos >= 16384) + (pos >= 20480) + (pos >= 21504) + (pos >= 21760);
  const float cnt = (float)(16 << (2 * d_lw[lvl]));
  const float* st = stats + ((((ti * 5 + lvl) * 16 + (plane >> 1))) << 1);
  const float mean = st[0] / cnt;
  const float var = st[1] / cnt - mean * mean;
  const float rstd = rsqrtf(var + 1e-5f);
  const float* gam = (tower ? g1 : g0) + plane * 8;
  const float* bet = (tower ? b1 : b0) + plane * 8;
  const size_t off = (size_t)ti * TIB + (size_t)plane * XP + (size_t)pos * 16;
  const uint4 d = *(const uint4*)((const char*)ybase + off);
  unsigned uu[4] = {d.x, d.y, d.z, d.w};
  unsigned ro[4];
#pragma unroll
  for (int k = 0; k < 4; k++) {
    const float f0 = __uint_as_float(uu[k] << 16);
    const float f1 = __uint_as_float(uu[k] & 0xFFFF0000u);
    const float o0 = fmaxf((f0 - mean) * rstd * gam[2 * k] + bet[2 * k], 0.f);
    const float o1 = fmaxf((f1 - mean) * rstd * gam[2 * k + 1] + bet[2 * k + 1], 0.f);
    ro[k] = (unsigned)f2bf(o0) | ((unsigned)f2bf(o1) << 16);
  }
  uint4 od = {ro[0], ro[1], ro[2], ro[3]};
  *(uint4*)((char*)xbase + off) = od;
}

// ---------------------------------------------------------------------------
extern "C" void kernel_launch(void* const* d_in, const int* in_sizes, int n_in,
                              void* d_out, int out_size, void* d_ws, size_t ws_size,
                              hipStream_t stream) {
  (void)in_sizes; (void)n_in; (void)out_size; (void)ws_size;
  char* ws = (char*)d_ws;
  unsigned short* zp = (unsigned short*)ws;                 // 1536 B zeros
  unsigned short* wblk = (unsigned short*)(ws + 2048);      // 8,257,536 B
  const size_t WSET_T = 1179648;                            // bytes per tower set
  const size_t WSET_O = 589824;                             // bytes per out set
  char* pXfeat = ws + 2048 + 6 * WSET_T + 2 * WSET_O;
  const size_t XSZ = (size_t)2 * 21824 * 256 * 2;           // 22,347,776 B
  char* pX = pXfeat + XSZ;                                  // 2 towers
  char* pY = pX + 2 * XSZ;                                  // 2 towers
  float* stats = (float*)(pY + 2 * XSZ);                    // 3 stages x 640 floats

  zpk<<<1, 256, 0, stream>>>((float*)zp, stats);
  wtrans<<<dim3(2304, 8), 256, 0, stream>>>(
      (const float*)d_in[5], (const float*)d_in[9], (const float*)d_in[13],
      (const float*)d_in[17], (const float*)d_in[21], (const float*)d_in[25],
      (const float*)d_in[29], (const float*)d_in[31], (const float*)d_in[33], wblk);
  feat_nhwc<<<dim3(341, 4, 2), 256, 0, stream>>>(
      (const float*)d_in[0], (const float*)d_in[1], (const float*)d_in[2],
      (const float*)d_in[3], (const float*)d_in[4], (unsigned short*)pXfeat);

  unsigned short* xc = (unsigned short*)pX;
  unsigned short* xr = (unsigned short*)(pX + XSZ);
  unsigned short* yc = (unsigned short*)pY;
  unsigned short* yr = (unsigned short*)(pY + XSZ);

  for (int s = 0; s < 3; s++) {
    const unsigned short* in0 = s ? xc : (unsigned short*)pXfeat;
    const unsigned short* in1 = s ? xr : (unsigned short*)pXfeat;
    const unsigned short* wc = wblk + (size_t)s * 589824;        // elem stride per set
    const unsigned short* wr = wblk + (size_t)(3 + s) * 589824;
    float* st_s = stats + (size_t)s * 640;
    conv_mfma<<<1368, 256, 0, stream>>>(
        in0, in1, wc, wr, yc, yr,
        (const float*)d_in[6 + 4 * s], (const float*)d_in[18 + 4 * s],
        nullptr, nullptr, nullptr, nullptr, zp, 0);
    gn_stats<<<dim3(13, 16, 4), 256, 0, stream>>>(yc, yr, st_s);
    gn_apply<<<10912, 256, 0, stream>>>(
        (const unsigned short*)pY, (unsigned short*)pX, st_s,
        (const float*)d_in[7 + 4 * s], (const float*)d_in[8 + 4 * s],
        (const float*)d_in[19 + 4 * s], (const float*)d_in[20 + 4 * s]);
  }
  const unsigned short* wo_c = wblk + (size_t)6 * 589824;
  const unsigned short* wo_r = wo_c + 294912;
  conv_mfma<<<684, 256, 0, stream>>>(
      xc, xr, wo_c, wo_r, nullptr, nullptr, nullptr, nullptr,
      (float*)d_out, (const float*)d_in[30], (const float*)d_in[32],
      (const float*)d_in[34], zp, 1);
}